// Round 6
// baseline (853.403 us; speedup 1.0000x reference)
//
#include <hip/hip_runtime.h>
#include <cstdint>

// Problem constants (fixed dataset: setup_inputs in reference)
constexpr int B = 8, N = 100000, G = 64, T = 256, TOPK = 27;
constexpr int BN = B * N;
constexpr int CAP = 1536;           // candidate LDS capacity per gt (E[cnt]~172)
constexpr int GPB = 2;              // gts per assign block
constexpr int TOKEN_BLOCKS = 2048;  // W2 grid: 8192 waves, fill-like sweep
#define NEG_INF_VAL (-100000000.0f) // -INF in reference, exactly representable

typedef float v4f __attribute__((ext_vector_type(4)));

// ---------------------------------------------------------------------------
// Kernel 0: precompute anchor centers (float2) once, and zero the best[]
// buffer. Same center formula as the assign/iou phases so distances are
// bit-identical.
// ---------------------------------------------------------------------------
__global__ __launch_bounds__(256) void atss_centers_kernel(
    const float* __restrict__ anchors, float2* __restrict__ ctr,
    unsigned long long* __restrict__ best)
{
#pragma clang fp contract(off)
  int i = blockIdx.x * 256 + threadIdx.x;
  if (i < BN) {
    float4 ab = ((const float4*)anchors)[i];
    ctr[i] = make_float2((ab.z + ab.x) * 0.5f, (ab.w + ab.y) * 0.5f);
    best[i] = 0ULL;
  }
}

// ---------------------------------------------------------------------------
// Kernel A: 2 gts per block (256 blocks x 1024 threads). Each block scans its
// batch's centers ONCE and tests each anchor against both gts: halves L2
// traffic (64->32 x 800 KB per XCD) and load-instruction count vs the 1-gt
// version; distance-test count is invariant. Per-gt candidate buffers,
// counts, adaptive radii -> candidate sets and all downstream math identical
// to the 1-gt version (rank-counting over (d, idx) keys is insertion-order
// independent).
// packed best = (f32bits(iou) << 32) | (0xFFFFFFFF - g)
//   -> max = largest iou; tie -> smallest g (matches jnp.argmax first-max).
// packed == 0 means "unmatched" (positives always have iou > 0).
// ---------------------------------------------------------------------------
__global__ __launch_bounds__(1024) void atss_assign_kernel(
    const float* __restrict__ anchors,     // [B,N,4]
    const float2* __restrict__ ctr,        // [B,N]
    const float* __restrict__ gts,         // [B,G,4]
    unsigned long long* __restrict__ best) // [B*N]
{
#pragma clang fp contract(off)
  __shared__ float s_d[GPB][CAP];
  __shared__ int   s_i[GPB][CAP];
  __shared__ int   s_cnt[GPB];
  __shared__ int   s_sel[GPB][TOPK];
  __shared__ float s_iou[GPB][TOPK];
  __shared__ int   s_in[GPB][TOPK];
  __shared__ float s_thresh;

  // XCD-bijective swizzle over 256 blocks: bid%8==k -> XCD k -> batch k
  // (32 pairs = 64 gts per batch). p = pair index in [0,256).
  const int bid = blockIdx.x;
  const int p   = (bid & 7) * 32 + (bid >> 3);
  const int b   = p >> 5;            // batch
  const int g0  = (p & 31) * 2;      // first gt of this pair within batch
  const int bg0 = b * G + g0;
  const int tid = threadIdx.x;

  const float4 gb0 = ((const float4*)gts)[bg0];
  const float4 gb1 = ((const float4*)gts)[bg0 + 1];
  const float gcx0 = (gb0.z + gb0.x) * 0.5f, gcy0 = (gb0.w + gb0.y) * 0.5f;
  const float gcx1 = (gb1.z + gb1.x) * 0.5f, gcy1 = (gb1.w + gb1.y) * 0.5f;

  const float4* abase = (const float4*)(anchors + (size_t)b * N * 4);
  const float4* c4    = (const float4*)(ctr + (size_t)b * N); // 2 centers/load

  // --- Candidate collection: all anchors with d^2 < thr^2, per gt. ---
  // Adaptive radius per gt; attempt 1 (thr=24) succeeds on this data.
  float thr2_0 = 576.0f, thr2_1 = 576.0f;
  int M0 = -1, M1 = -1; // -1 = unresolved (uniform across threads)
  for (int attempt = 0; attempt < 8 && (M0 < 0 || M1 < 0); ++attempt) {
    if (tid == 0 && M0 < 0) s_cnt[0] = 0;
    if (tid == 1 && M1 < 0) s_cnt[1] = 0;
    __syncthreads();
    const bool a0 = (M0 < 0), a1 = (M1 < 0);

#define ATSS_TEST(cx, cy, idx)                                                \
  do {                                                                        \
    if (a0) {                                                                 \
      float dx = (cx) - gcx0, dy = (cy) - gcy0;                               \
      float d2 = __fmul_rn(dx, dx) + __fmul_rn(dy, dy);                       \
      if (d2 < thr2_0) {                                                      \
        int q_ = atomicAdd(&s_cnt[0], 1);                                     \
        if (q_ < CAP) { s_d[0][q_] = __fsqrt_rn(d2); s_i[0][q_] = (idx); }    \
      }                                                                       \
    }                                                                         \
    if (a1) {                                                                 \
      float dx = (cx) - gcx1, dy = (cy) - gcy1;                               \
      float d2 = __fmul_rn(dx, dx) + __fmul_rn(dy, dy);                       \
      if (d2 < thr2_1) {                                                      \
        int q_ = atomicAdd(&s_cnt[1], 1);                                     \
        if (q_ < CAP) { s_d[1][q_] = __fsqrt_rn(d2); s_i[1][q_] = (idx); }    \
      }                                                                       \
    }                                                                         \
  } while (0)

    for (int m = tid; m < N / 4; m += 1024) {
      float4 ca = c4[2 * m];
      float4 cb = c4[2 * m + 1];
      ATSS_TEST(ca.x, ca.y, 4 * m);
      ATSS_TEST(ca.z, ca.w, 4 * m + 1);
      ATSS_TEST(cb.x, cb.y, 4 * m + 2);
      ATSS_TEST(cb.z, cb.w, 4 * m + 3);
    }
#undef ATSS_TEST
    __syncthreads();
    const int c0 = s_cnt[0], c1 = s_cnt[1];
    __syncthreads();
    if (M0 < 0) {
      if (c0 >= TOPK && c0 <= CAP) M0 = c0;
      else thr2_0 *= (c0 < TOPK) ? 16.0f : 0.25f;
    }
    if (M1 < 0) {
      if (c1 >= TOPK && c1 <= CAP) M1 = c1;
      else thr2_1 *= (c1 < TOPK) ? 16.0f : 0.25f;
    }
  }

  // --- Per-gt: exact top-27 by rank counting, IoU, threshold, scatter. ---
  for (int q = 0; q < GPB; ++q) {
    const int M = (q == 0) ? M0 : M1;
    const float4 gbox = (q == 0) ? gb0 : gb1;
    const int g = g0 + q;

    // Rank counting over (d, idx) lexicographic keys: keys distinct (idx
    // unique) -> ranks unique; rank k = k-th nearest, same order lax.top_k
    // produces (preserves mean/std sum order).
    for (int s = tid; s < M; s += 1024) {
      unsigned long long pk_s =
          ((unsigned long long)__float_as_uint(s_d[q][s]) << 20) |
          (unsigned long long)(unsigned)s_i[q][s];
      int rank = 0;
      for (int j = 0; j < M; ++j) {
        unsigned long long pk_j =
            ((unsigned long long)__float_as_uint(s_d[q][j]) << 20) |
            (unsigned long long)(unsigned)s_i[q][j];
        rank += (pk_j < pk_s) ? 1 : 0;
      }
      if (rank < TOPK) s_sel[q][rank] = s_i[q][s];
    }
    __syncthreads();

    // Candidate IoU + center-inside test.
    if (tid < TOPK) {
      int a = s_sel[q][tid];
      float4 ab = abase[a];
      float area_a = __fmul_rn(ab.z - ab.x, ab.w - ab.y);
      float area_b = __fmul_rn(gbox.z - gbox.x, gbox.w - gbox.y);
      float ltx = fmaxf(ab.x, gbox.x), lty = fmaxf(ab.y, gbox.y);
      float rbx = fminf(ab.z, gbox.z), rby = fminf(ab.w, gbox.w);
      float w = fmaxf(rbx - ltx, 0.0f), h = fmaxf(rby - lty, 0.0f);
      float inter = __fmul_rn(w, h);
      float uni = (area_a + area_b) - inter;
      s_iou[q][tid] = inter / uni;
      float acx = (ab.z + ab.x) * 0.5f, acy = (ab.w + ab.y) * 0.5f;
      float l = acx - gbox.x, t = acy - gbox.y;
      float r = gbox.z - acx, bt = gbox.w - acy;
      float mn = fminf(fminf(l, t), fminf(r, bt));
      s_in[q][tid] = (mn > 0.01f) ? 1 : 0;
    }
    __syncthreads();

    // mean + unbiased std threshold (ddof=1). Same order as reference.
    if (tid == 0) {
      float sum = 0.0f;
      for (int k = 0; k < TOPK; ++k) sum += s_iou[q][k];
      float mean = sum / (float)TOPK;
      float vs = 0.0f;
      for (int k = 0; k < TOPK; ++k) {
        float d = s_iou[q][k] - mean;
        vs += __fmul_rn(d, d);
      }
      float sd = __fsqrt_rn(vs / (float)(TOPK - 1));
      s_thresh = mean + sd;
    }
    __syncthreads();

    // Scatter positives.
    if (tid < TOPK) {
      float iou = s_iou[q][tid];
      if (s_in[q][tid] && iou >= s_thresh) {
        unsigned long long pk =
            ((unsigned long long)__float_as_uint(iou) << 32) |
            (unsigned long long)(0xFFFFFFFFu - (unsigned)g);
        atomicMax(&best[(size_t)b * N + s_sel[q][tid]], pk);
      }
    }
    __syncthreads(); // s_thresh reused by next q
  }
}

// ---------------------------------------------------------------------------
// Kernel W1: val / idx / matched_gts. One thread per anchor, fully coalesced.
// ---------------------------------------------------------------------------
__global__ __launch_bounds__(256) void atss_scalar_write_kernel(
    const unsigned long long* __restrict__ best, // [B*N]
    const float* __restrict__ gts,               // [B,G,4]
    float* __restrict__ out)
{
  float* __restrict__ out_val = out;
  float* __restrict__ out_idx = out + (size_t)BN;
  float* __restrict__ out_mg  = out + (size_t)2 * BN;

  const int i = blockIdx.x * 256 + threadIdx.x;
  unsigned long long p = best[i];
  const int b_ = i / N;
  int g = 0;
  float val = NEG_INF_VAL;
  if (p != 0ULL) {
    g   = (int)(0xFFFFFFFFu - (unsigned)(p & 0xFFFFFFFFULL));
    val = __uint_as_float((unsigned)(p >> 32));
  }
  const int row = b_ * G + g; // unmatched -> g=0 (matches argmax of all -INF)
  out_val[i] = val;
  out_idx[i] = (float)g;
  ((v4f*)out_mg)[i] = ((const v4f*)gts)[row];
}

// ---------------------------------------------------------------------------
// Kernel W2: token rows. One wave per 1 KB row, grid-strided sweep (round-4
// null vs round-3 per-block streams: both at the store floor; keep this one).
// best[row] is a wave-uniform broadcast read, software-pipelined one row
// ahead; row/N division only on the ~3% matched path.
// ---------------------------------------------------------------------------
__global__ __launch_bounds__(256) void atss_token_kernel(
    const unsigned long long* __restrict__ best, // [B*N]
    const float* __restrict__ tokens,            // [B,G,T]
    float* __restrict__ out)
{
  float* __restrict__ out_tok = out + (size_t)6 * BN;
  const int lane = threadIdx.x & 63;
  const int NW   = TOKEN_BLOCKS * 4;                       // 8192 waves
  int row = (blockIdx.x << 2) | (threadIdx.x >> 6);        // global wave id
  const v4f* tok4 = (const v4f*)tokens;

  unsigned long long p = best[row];
  while (true) {
    const int nrow = row + NW;
    unsigned long long pn = (nrow < BN) ? best[nrow] : 0ULL; // prefetch next
    v4f t;
    if (p != 0ULL) {
      const int b_ = row / N;
      const int g  = (int)(0xFFFFFFFFu - (unsigned)(p & 0xFFFFFFFFULL));
      t = tok4[(size_t)(b_ * G + g) * 64 + lane];
    } else {
      t = (v4f){0.0f, 0.0f, 0.0f, 0.0f};
      if (lane == 63) t.w = 1.0f; // unmatched one-hot at token T-1
    }
    ((v4f*)(out_tok + (size_t)row * T))[lane] = t;
    if (nrow >= BN) break;
    row = nrow;
    p = pn;
  }
}

extern "C" void kernel_launch(void* const* d_in, const int* in_sizes, int n_in,
                              void* d_out, int out_size, void* d_ws, size_t ws_size,
                              hipStream_t stream) {
  const float* anchors = (const float*)d_in[0]; // [B,N,4]
  const float* gts     = (const float*)d_in[1]; // [B,G,4]
  const float* tokens  = (const float*)d_in[2]; // [B,G,T]
  float* out = (float*)d_out;

  unsigned long long* best = (unsigned long long*)d_ws;        // B*N u64 = 6.4 MB
  float2* ctr = (float2*)((char*)d_ws + sizeof(unsigned long long) * (size_t)BN);

  atss_centers_kernel<<<BN / 256, 256, 0, stream>>>(anchors, ctr, best);
  atss_assign_kernel<<<B * G / GPB, 1024, 0, stream>>>(anchors, ctr, gts, best);
  atss_scalar_write_kernel<<<BN / 256, 256, 0, stream>>>(best, gts, out);
  atss_token_kernel<<<TOKEN_BLOCKS, 256, 0, stream>>>(best, tokens, out);
}